// Round 1
// baseline (318.535 us; speedup 1.0000x reference)
//
#include <hip/hip_runtime.h>
#include <hip/hip_fp16.h>

// ---------------------------------------------------------------------------
// GCN 2-layer (PyG GCNConv) on MI355X — R15.
// R14 profile: k_agg1 = 57.5us top kernel, VALUBusy 76%, MfmaUtil 0, HBM 35%,
// occupancy 67% @ 32 VGPR (not reg-limited). Implied ~530 VALU/wave vs ~230
// expected -> agg1 is VALU/latency-overhead bound, not traffic bound.
// Delta vs R14 (one unit: k_agg1 rewrite, all other kernels byte-identical):
//   (a) deg-dispatched single-pass unroll: 32 slots (deg<=32, P=.54) or 64
//       slots (P(deg>64)~1e-7) -> one csr phase + 8 gathers in flight instead
//       of 1.46 serial 4-gather iterations.
//   (b) 32-bit saddr gather addressing ((row<<7)+s*16 byte offset) -> kills
//       per-edge 64-bit address chains.
//   (c) DPP epilogue: group-reduce = add_dpp(row_ror:8) + ds_swizzle(xor16) +
//       shfl(32); p-reduce = quad_perm 0xB1/0x4E + half_mirror. DS 27 -> 16.
//   (d) readfirstlane'd wid/off0/off1 (scalar bounds, like k_agg2).
//   Index clamp to off1-1 KEPT: dropping it would gather neighbor rows
//   (+~188MB real fabric traffic); clamped slots re-hit a hot L1 line.
// Predict: agg1 57.5 -> ~45us, FETCH unchanged ~157MB, total 291 -> ~278us.
// If neutral with VALUBusy down -> fabric-bound at ~2.8TB/s; next: cut bytes.
// ---------------------------------------------------------------------------

#define BSHIFT 9
#define BSIZE 512            // nodes per bucket
#define NBUCKET 256          // max buckets (requires N <= 131072)

typedef _Float16 f16x8 __attribute__((ext_vector_type(8)));
typedef float    f32x4 __attribute__((ext_vector_type(4)));

// ---------------- CSR build (identical to R14) ----------------

__global__ __launch_bounds__(1024) void k_hist(const int* __restrict__ col,
                                               int* __restrict__ hist, int E4) {
    __shared__ int h[NBUCKET];
    int t = threadIdx.x, bl = blockIdx.x;
    if (t < NBUCKET) h[t] = 0;
    __syncthreads();
#pragma unroll
    for (int i = 0; i < 4; ++i) {
        int idx = bl * 4096 + i * 1024 + t;
        if (idx < E4) {
            int4 c = ((const int4*)col)[idx];
            atomicAdd(&h[c.x >> BSHIFT], 1);
            atomicAdd(&h[c.y >> BSHIFT], 1);
            atomicAdd(&h[c.z >> BSHIFT], 1);
            atomicAdd(&h[c.w >> BSHIFT], 1);
        }
    }
    __syncthreads();
    if (t < NBUCKET) hist[bl * NBUCKET + t] = h[t];
}

__global__ __launch_bounds__(256) void k_scan_bucket(const int* __restrict__ hist,
                                                     int* __restrict__ histS,
                                                     int* __restrict__ tot, int nbl) {
    __shared__ int A[2][256];
    int b = blockIdx.x, t = threadIdx.x;
    A[0][t] = (t < nbl) ? hist[t * NBUCKET + b] : 0;
    __syncthreads();
    int src = 0;
    for (int off = 1; off < 256; off <<= 1) {
        A[1 - src][t] = A[src][t] + ((t >= off) ? A[src][t - off] : 0);
        src ^= 1;
        __syncthreads();
    }
    if (t < nbl) histS[b * nbl + t] = (t > 0) ? A[src][t - 1] : 0;
    if (t == 0) tot[b] = A[src][nbl - 1];
}

__global__ __launch_bounds__(256) void k_scan_tot(const int* __restrict__ tot,
                                                  int* __restrict__ base) {
    __shared__ int A[2][NBUCKET];
    int t = threadIdx.x;
    A[0][t] = tot[t];
    __syncthreads();
    int src = 0;
    for (int off = 1; off < NBUCKET; off <<= 1) {
        A[1 - src][t] = A[src][t] + ((t >= off) ? A[src][t - off] : 0);
        src ^= 1;
        __syncthreads();
    }
    base[t] = (t > 0) ? A[src][t - 1] : 0;
    if (t == 255) base[NBUCKET] = A[src][255];
}

__global__ __launch_bounds__(1024) void k_scatter(const int* __restrict__ ei,
                                                  const float* __restrict__ ea,
                                                  const int* __restrict__ histS,
                                                  const int* __restrict__ base,
                                                  int2* __restrict__ binned,
                                                  int E, int E4, int nbl) {
    __shared__ int cur[NBUCKET];
    int t = threadIdx.x, bl = blockIdx.x;
    if (t < NBUCKET) cur[t] = base[t] + histS[t * nbl + bl];
    __syncthreads();
#pragma unroll
    for (int i = 0; i < 4; ++i) {
        int idx = bl * 4096 + i * 1024 + t;
        if (idx < E4) {
            int4   r = ((const int4*)ei)[idx];
            int4   c = ((const int4*)(ei + E))[idx];
            float4 w = ((const float4*)ea)[idx];
            int p;
            p = atomicAdd(&cur[c.x >> BSHIFT], 1);
            binned[p] = make_int2(((c.x & (BSIZE - 1)) << 17) | r.x, __float_as_int(w.x));
            p = atomicAdd(&cur[c.y >> BSHIFT], 1);
            binned[p] = make_int2(((c.y & (BSIZE - 1)) << 17) | r.y, __float_as_int(w.y));
            p = atomicAdd(&cur[c.z >> BSHIFT], 1);
            binned[p] = make_int2(((c.z & (BSIZE - 1)) << 17) | r.z, __float_as_int(w.z));
            p = atomicAdd(&cur[c.w >> BSHIFT], 1);
            binned[p] = make_int2(((c.w & (BSIZE - 1)) << 17) | r.w, __float_as_int(w.w));
        }
    }
}

__global__ __launch_bounds__(1024) void k_finalize(const int2* __restrict__ binned,
                                                   const int* __restrict__ base,
                                                   unsigned* __restrict__ csr,
                                                   int* __restrict__ offset,
                                                   float* __restrict__ dinv,
                                                   int N, int E) {
    __shared__ int   cnt[BSIZE];
    __shared__ float fsum[BSIZE];
    __shared__ int   inc[2][BSIZE];
    __shared__ int   cur[BSIZE];
    int b = blockIdx.x, t = threadIdx.x;
    int e0 = base[b], e1 = base[b + 1];
    for (int i = t; i < BSIZE; i += 1024) { cnt[i] = 0; fsum[i] = 0.f; }
    __syncthreads();
    for (int e = e0 + t; e < e1; e += 1024) {
        int2 ed = binned[e];
        unsigned cl = ((unsigned)ed.x) >> 17;
        atomicAdd(&cnt[cl], 1);
        atomicAdd(&fsum[cl], __int_as_float(ed.y));
    }
    __syncthreads();
    for (int i = t; i < BSIZE; i += 1024) inc[0][i] = cnt[i];
    __syncthreads();
    int src = 0;
    for (int off = 1; off < BSIZE; off <<= 1) {
        for (int i = t; i < BSIZE; i += 1024)
            inc[1 - src][i] = inc[src][i] + ((i >= off) ? inc[src][i - off] : 0);
        src ^= 1;
        __syncthreads();
    }
    int nodeBase = b << BSHIFT;
    for (int i = t; i < BSIZE; i += 1024) {
        int ex = (i > 0) ? inc[src][i - 1] : 0;
        cur[i] = e0 + ex;
        int node = nodeBase + i;
        if (node < N) {
            offset[node] = e0 + ex;
            dinv[node]   = rsqrtf(1.0f + fsum[i]);
        }
    }
    if (b == 0 && t == 0) offset[N] = E;
    __syncthreads();
    for (int e = e0 + t; e < e1; e += 1024) {
        int2 ed = binned[e];
        unsigned cl = ((unsigned)ed.x) >> 17;
        unsigned row = ((unsigned)ed.x) & 0x1FFFF;
        unsigned hb = (unsigned)__half_as_ushort(__float2half_rn(__int_as_float(ed.y))) & 0x7FFFu;
        int p = atomicAdd(&cur[cl], 1);
        csr[p] = (hb << 17) | row;
    }
}

// ---------------- dense compute ----------------

__global__ __launch_bounds__(256) void k_gemm_mfma(const float* __restrict__ x,
                                                   const float* __restrict__ W1,
                                                   const float* __restrict__ dinv,
                                                   __half* __restrict__ hs, int n) {
    __shared__ _Float16 xh[64][136];
    __shared__ _Float16 wTh[64][136];
    int t = threadIdx.x;
    int nodeBase = blockIdx.x * 64;

    for (int i = t; i < 2048; i += 256) {
        int r = i >> 5, c4 = i & 31;
        int node = nodeBase + r;
        float4 v = make_float4(0.f, 0.f, 0.f, 0.f);
        if (node < n) v = ((const float4*)x)[node * 32 + c4];
        _Float16* dst = &xh[r][c4 * 4];
        dst[0] = (_Float16)v.x; dst[1] = (_Float16)v.y;
        dst[2] = (_Float16)v.z; dst[3] = (_Float16)v.w;
    }
    for (int i = t; i < 2048; i += 256) {
        int k = i >> 4, c4 = i & 15;
        float4 v = ((const float4*)W1)[k * 16 + c4];
        wTh[c4 * 4 + 0][k] = (_Float16)v.x;
        wTh[c4 * 4 + 1][k] = (_Float16)v.y;
        wTh[c4 * 4 + 2][k] = (_Float16)v.z;
        wTh[c4 * 4 + 3][k] = (_Float16)v.w;
    }
    __syncthreads();

    int w = t >> 6, lane = t & 63;
    int m = lane & 15, quad = lane >> 4;

    f32x4 acc[4] = {{0.f,0.f,0.f,0.f},{0.f,0.f,0.f,0.f},
                    {0.f,0.f,0.f,0.f},{0.f,0.f,0.f,0.f}};
#pragma unroll
    for (int ks = 0; ks < 128; ks += 32) {
        f16x8 a = *(const f16x8*)&xh[w * 16 + m][ks + quad * 8];
#pragma unroll
        for (int ct = 0; ct < 4; ++ct) {
            f16x8 bfr = *(const f16x8*)&wTh[ct * 16 + m][ks + quad * 8];
            acc[ct] = __builtin_amdgcn_mfma_f32_16x16x32_f16(a, bfr, acc[ct], 0, 0, 0);
        }
    }

#pragma unroll
    for (int reg = 0; reg < 4; ++reg) {
        int node = nodeBase + w * 16 + quad * 4 + reg;
        if (node < n) {
            float dv = dinv[node];
#pragma unroll
            for (int ct = 0; ct < 4; ++ct) {
                float v = acc[ct][reg] * dv;
                hs[(size_t)node * 64 + ct * 16 + m] = __float2half_rn(v);
            }
        }
    }
}

// ---------------- agg1 (R15 rewrite) ----------------

__device__ __forceinline__ float dpp_ror8(float x) {
    // row_ror:8 == xor 8 within each 16-lane row
    return __int_as_float(__builtin_amdgcn_update_dpp(
        0, __float_as_int(x), 0x128, 0xF, 0xF, true));
}
template<int CTRL>
__device__ __forceinline__ float dpp_mov(float x) {
    return __int_as_float(__builtin_amdgcn_update_dpp(
        0, __float_as_int(x), CTRL, 0xF, 0xF, true));
}
__device__ __forceinline__ float swz_xor16(float x) {
    // bitmode swizzle: and=0x1F, or=0, xor=0x10 -> lane ^ 16 (within 32-group)
    return __int_as_float(__builtin_amdgcn_ds_swizzle(__float_as_int(x), 0x401F));
}

// Process M slot-rounds (8*M edge slots across 8 lane-groups), slots
// i = j + 8*m for this group's base j. Clamped slots re-read csr[off1-1]
// (hot line) with w=0 so no extra fabric traffic is generated.
template<int M>
__device__ __forceinline__ void agg_slots(const unsigned* __restrict__ csr,
                                          const char* __restrict__ hsB,
                                          int j, int off1, unsigned sbyte,
                                          float* __restrict__ acc) {
    unsigned e[M];
    f16x8    v[M];
#pragma unroll
    for (int m = 0; m < M; ++m) {
        int i = j + 8 * m;
        e[m] = csr[(i < off1) ? i : off1 - 1];
    }
#pragma unroll
    for (int m = 0; m < M; ++m)
        v[m] = *(const f16x8*)(hsB + ((e[m] & 0x1FFFFu) << 7) + sbyte);
#pragma unroll
    for (int m = 0; m < M; ++m) {
        int i = j + 8 * m;
        float w = (i < off1)
                  ? (float)__ushort_as_half((unsigned short)(e[m] >> 17)) : 0.f;
#pragma unroll
        for (int k = 0; k < 8; ++k) acc[k] += w * (float)v[m][k];
    }
}

__global__ __launch_bounds__(256, 6) void k_agg1(const __half* __restrict__ hs,
                                                 const int* __restrict__ offset,
                                                 const unsigned* __restrict__ csr,
                                                 const float* __restrict__ dinv,
                                                 const float* __restrict__ b1,
                                                 const float* __restrict__ W2,
                                                 float* __restrict__ h2s, int n) {
    int wid  = __builtin_amdgcn_readfirstlane(
                   (int)((blockIdx.x * blockDim.x + threadIdx.x) >> 6));
    int lane = threadIdx.x & 63;
    if (wid >= n) return;
    int off0 = __builtin_amdgcn_readfirstlane(offset[wid]);
    int off1 = __builtin_amdgcn_readfirstlane(offset[wid + 1]);
    int g = lane >> 3, s = lane & 7;
    unsigned sbyte = (unsigned)s << 4;          // s * 16 bytes
    const char* hsB = (const char*)hs;

    float di = dinv[wid];
    float acc[8] = {0.f, 0.f, 0.f, 0.f, 0.f, 0.f, 0.f, 0.f};

    {   // self loop (weight 1; dinv factors applied via hs scaling + di below)
        f16x8 v = *(const f16x8*)(hsB + ((unsigned)wid << 7) + sbyte);
        if (g == 0) {
#pragma unroll
            for (int k = 0; k < 8; ++k) acc[k] += (float)v[k];
        }
    }

    int deg = off1 - off0;
    if (deg > 0) {
        if (deg <= 32) {
            // P(deg<=32) ~= 0.54: one 32-slot pass, 4 gathers in flight
            agg_slots<4>(csr, hsB, off0 + g, off1, sbyte, acc);
        } else {
            // P(32<deg<=64) ~= 0.46: one 64-slot pass, 8 gathers in flight
            agg_slots<8>(csr, hsB, off0 + g, off1, sbyte, acc);
            // P(deg>64) ~ 1e-7 for Poisson(32): rare residual
            for (int j = off0 + 64; j < off1; j += 32)
                agg_slots<4>(csr, hsB, j + g, off1, sbyte, acc);
        }
    }

    // reduce over groups (lane bits 3,4,5): DPP ror8 + swizzle xor16 + shfl32
#pragma unroll
    for (int k = 0; k < 8; ++k) {
        float t = acc[k];
        t += dpp_ror8(t);
        t += swz_xor16(t);
        t += __shfl_xor(t, 32);
        acc[k] = t;
    }

    float4 bA = ((const float4*)b1)[s * 2], bB = ((const float4*)b1)[s * 2 + 1];
    float4 wA = ((const float4*)W2)[s * 2], wB = ((const float4*)W2)[s * 2 + 1];
    float p = 0.f;
    p += fmaxf(di * acc[0] + bA.x, 0.f) * wA.x;
    p += fmaxf(di * acc[1] + bA.y, 0.f) * wA.y;
    p += fmaxf(di * acc[2] + bA.z, 0.f) * wA.z;
    p += fmaxf(di * acc[3] + bA.w, 0.f) * wA.w;
    p += fmaxf(di * acc[4] + bB.x, 0.f) * wB.x;
    p += fmaxf(di * acc[5] + bB.y, 0.f) * wB.y;
    p += fmaxf(di * acc[6] + bB.z, 0.f) * wB.z;
    p += fmaxf(di * acc[7] + bB.w, 0.f) * wB.w;
    // reduce over s (lane bits 0,1,2): pure DPP
    p += dpp_mov<0xB1>(p);    // quad_perm [1,0,3,2] == xor 1
    p += dpp_mov<0x4E>(p);    // quad_perm [2,3,0,1] == xor 2
    p += dpp_mov<0x141>(p);   // row_half_mirror == xor 4 after 1,2 reduced
    if (lane == 0) h2s[wid] = di * p;
}

// ---------------- agg2 (identical to R14) ----------------

__global__ __launch_bounds__(256) void k_agg2(const float* __restrict__ h2s,
                                              const int* __restrict__ offset,
                                              const unsigned* __restrict__ csr,
                                              const float* __restrict__ dinv,
                                              const float* __restrict__ b2,
                                              float* __restrict__ out, int n) {
    int wid = __builtin_amdgcn_readfirstlane((int)((blockIdx.x * blockDim.x + threadIdx.x) >> 6));
    int lane = threadIdx.x & 63;
    if (wid >= n) return;
    int off0 = __builtin_amdgcn_readfirstlane(offset[wid]);
    int off1 = __builtin_amdgcn_readfirstlane(offset[wid + 1]);
    float di = dinv[wid];
    float p = 0.f;
    for (int e = off0 + lane; e < off1; e += 64) {
        unsigned ed = csr[e];
        p += (float)__ushort_as_half((unsigned short)(ed >> 17)) * h2s[ed & 0x1FFFF];
    }
#pragma unroll
    for (int s = 32; s > 0; s >>= 1) p += __shfl_xor(p, s);
    if (lane == 0) out[wid] = di * (p + h2s[wid]) + b2[0];
}

extern "C" void kernel_launch(void* const* d_in, const int* in_sizes, int n_in,
                              void* d_out, int out_size, void* d_ws, size_t ws_size,
                              hipStream_t stream) {
    const float* x  = (const float*)d_in[0];
    const int*   ei = (const int*)  d_in[1];
    const float* ea = (const float*)d_in[2];
    const float* W1 = (const float*)d_in[3];
    const float* b1 = (const float*)d_in[4];
    const float* W2 = (const float*)d_in[5];
    const float* b2 = (const float*)d_in[6];
    float* out = (float*)d_out;

    const int N  = in_sizes[0] / 128;   // 100000 (must be <= 131072)
    const int E  = in_sizes[2];         // 3200000
    const int E4 = E / 4;
    const int nbl  = (E4 + 4095) / 4096;        // 16384-edge chunks (196)
    const int nbkt = (N + BSIZE - 1) / BSIZE;   // active buckets (196)

    char* p = (char*)d_ws;
    auto alloc = [&](size_t bytes) -> void* {
        void* r = (void*)p;
        p += (bytes + 255) & ~(size_t)255;
        return r;
    };
    int*       hist   = (int*)      alloc((size_t)nbl * NBUCKET * 4);
    int*       histS  = (int*)      alloc((size_t)NBUCKET * nbl * 4);
    int*       tot    = (int*)      alloc((size_t)NBUCKET * 4);
    int*       base   = (int*)      alloc((size_t)(NBUCKET + 1) * 4);
    int2*      binned = (int2*)     alloc((size_t)E * 8);
    unsigned*  csr    = (unsigned*) alloc((size_t)E * 4);
    int*       offset = (int*)      alloc((size_t)(N + 1) * 4);
    float*     dinv   = (float*)    alloc((size_t)N * 4);
    __half*    hs     = (__half*)   alloc((size_t)N * 64 * 2);
    float*     h2s    = (float*)    alloc((size_t)N * 4);

    const int nb_gemm = (N + 63) / 64;
    const int nb_wave = (N * 64 + 255) / 256;   // one 64-wide wave per node

    k_hist<<<nbl, 1024, 0, stream>>>(ei + E, hist, E4);
    k_scan_bucket<<<NBUCKET, 256, 0, stream>>>(hist, histS, tot, nbl);
    k_scan_tot<<<1, 256, 0, stream>>>(tot, base);
    k_scatter<<<nbl, 1024, 0, stream>>>(ei, ea, histS, base, binned, E, E4, nbl);
    k_finalize<<<nbkt, 1024, 0, stream>>>(binned, base, csr, offset, dinv, N, E);
    k_gemm_mfma<<<nb_gemm, 256, 0, stream>>>(x, W1, dinv, hs, N);
    k_agg1<<<nb_wave, 256, 0, stream>>>(hs, offset, csr, dinv, b1, W2, h2s, N);
    k_agg2<<<nb_wave, 256, 0, stream>>>(h2s, offset, csr, dinv, b2, out, N);
}

// Round 2
// 287.516 us; speedup vs baseline: 1.1079x; 1.1079x over previous
//
#include <hip/hip_runtime.h>
#include <hip/hip_fp16.h>

// ---------------------------------------------------------------------------
// GCN 2-layer (PyG GCNConv) on MI355X — R16.
// R15 post-mortem: deg-dispatched 64-slot unroll spilled one f16x8 per lane
// (WRITE_SIZE 0.8MB -> 97.8MB = 100K waves * 64 lanes * 16B; FETCH +42MB;
// VALUBusy 76->50; dur 57.5->80.5us). Instruction savings were real but
// drowned by scratch traffic.
// R16 = R14 loop structure (4 gathers in flight, no helper-fn acc pointer,
// no min-waves launch_bounds) + the three non-spilling R15 deltas:
//   (b) 32-bit byte-offset gather addressing ((row<<7)+s*16)
//   (c) DPP epilogue (row_ror:8 + swizzle xor16 + shfl32; quad_perm/mirror)
//   (d) readfirstlane'd scalar wid/off0/off1
// All other kernels byte-identical to R14/R15.
// Predict: WRITE back to ~0.8MB, FETCH ~157MB, VGPR ~32, agg1 ~50us,
// total ~283us. If agg1 ~57us: latency-bound -> next cut bytes/gather.
// ---------------------------------------------------------------------------

#define BSHIFT 9
#define BSIZE 512            // nodes per bucket
#define NBUCKET 256          // max buckets (requires N <= 131072)

typedef _Float16 f16x8 __attribute__((ext_vector_type(8)));
typedef float    f32x4 __attribute__((ext_vector_type(4)));

// ---------------- CSR build (identical to R14) ----------------

__global__ __launch_bounds__(1024) void k_hist(const int* __restrict__ col,
                                               int* __restrict__ hist, int E4) {
    __shared__ int h[NBUCKET];
    int t = threadIdx.x, bl = blockIdx.x;
    if (t < NBUCKET) h[t] = 0;
    __syncthreads();
#pragma unroll
    for (int i = 0; i < 4; ++i) {
        int idx = bl * 4096 + i * 1024 + t;
        if (idx < E4) {
            int4 c = ((const int4*)col)[idx];
            atomicAdd(&h[c.x >> BSHIFT], 1);
            atomicAdd(&h[c.y >> BSHIFT], 1);
            atomicAdd(&h[c.z >> BSHIFT], 1);
            atomicAdd(&h[c.w >> BSHIFT], 1);
        }
    }
    __syncthreads();
    if (t < NBUCKET) hist[bl * NBUCKET + t] = h[t];
}

__global__ __launch_bounds__(256) void k_scan_bucket(const int* __restrict__ hist,
                                                     int* __restrict__ histS,
                                                     int* __restrict__ tot, int nbl) {
    __shared__ int A[2][256];
    int b = blockIdx.x, t = threadIdx.x;
    A[0][t] = (t < nbl) ? hist[t * NBUCKET + b] : 0;
    __syncthreads();
    int src = 0;
    for (int off = 1; off < 256; off <<= 1) {
        A[1 - src][t] = A[src][t] + ((t >= off) ? A[src][t - off] : 0);
        src ^= 1;
        __syncthreads();
    }
    if (t < nbl) histS[b * nbl + t] = (t > 0) ? A[src][t - 1] : 0;
    if (t == 0) tot[b] = A[src][nbl - 1];
}

__global__ __launch_bounds__(256) void k_scan_tot(const int* __restrict__ tot,
                                                  int* __restrict__ base) {
    __shared__ int A[2][NBUCKET];
    int t = threadIdx.x;
    A[0][t] = tot[t];
    __syncthreads();
    int src = 0;
    for (int off = 1; off < NBUCKET; off <<= 1) {
        A[1 - src][t] = A[src][t] + ((t >= off) ? A[src][t - off] : 0);
        src ^= 1;
        __syncthreads();
    }
    base[t] = (t > 0) ? A[src][t - 1] : 0;
    if (t == 255) base[NBUCKET] = A[src][255];
}

__global__ __launch_bounds__(1024) void k_scatter(const int* __restrict__ ei,
                                                  const float* __restrict__ ea,
                                                  const int* __restrict__ histS,
                                                  const int* __restrict__ base,
                                                  int2* __restrict__ binned,
                                                  int E, int E4, int nbl) {
    __shared__ int cur[NBUCKET];
    int t = threadIdx.x, bl = blockIdx.x;
    if (t < NBUCKET) cur[t] = base[t] + histS[t * nbl + bl];
    __syncthreads();
#pragma unroll
    for (int i = 0; i < 4; ++i) {
        int idx = bl * 4096 + i * 1024 + t;
        if (idx < E4) {
            int4   r = ((const int4*)ei)[idx];
            int4   c = ((const int4*)(ei + E))[idx];
            float4 w = ((const float4*)ea)[idx];
            int p;
            p = atomicAdd(&cur[c.x >> BSHIFT], 1);
            binned[p] = make_int2(((c.x & (BSIZE - 1)) << 17) | r.x, __float_as_int(w.x));
            p = atomicAdd(&cur[c.y >> BSHIFT], 1);
            binned[p] = make_int2(((c.y & (BSIZE - 1)) << 17) | r.y, __float_as_int(w.y));
            p = atomicAdd(&cur[c.z >> BSHIFT], 1);
            binned[p] = make_int2(((c.z & (BSIZE - 1)) << 17) | r.z, __float_as_int(w.z));
            p = atomicAdd(&cur[c.w >> BSHIFT], 1);
            binned[p] = make_int2(((c.w & (BSIZE - 1)) << 17) | r.w, __float_as_int(w.w));
        }
    }
}

__global__ __launch_bounds__(1024) void k_finalize(const int2* __restrict__ binned,
                                                   const int* __restrict__ base,
                                                   unsigned* __restrict__ csr,
                                                   int* __restrict__ offset,
                                                   float* __restrict__ dinv,
                                                   int N, int E) {
    __shared__ int   cnt[BSIZE];
    __shared__ float fsum[BSIZE];
    __shared__ int   inc[2][BSIZE];
    __shared__ int   cur[BSIZE];
    int b = blockIdx.x, t = threadIdx.x;
    int e0 = base[b], e1 = base[b + 1];
    for (int i = t; i < BSIZE; i += 1024) { cnt[i] = 0; fsum[i] = 0.f; }
    __syncthreads();
    for (int e = e0 + t; e < e1; e += 1024) {
        int2 ed = binned[e];
        unsigned cl = ((unsigned)ed.x) >> 17;
        atomicAdd(&cnt[cl], 1);
        atomicAdd(&fsum[cl], __int_as_float(ed.y));
    }
    __syncthreads();
    for (int i = t; i < BSIZE; i += 1024) inc[0][i] = cnt[i];
    __syncthreads();
    int src = 0;
    for (int off = 1; off < BSIZE; off <<= 1) {
        for (int i = t; i < BSIZE; i += 1024)
            inc[1 - src][i] = inc[src][i] + ((i >= off) ? inc[src][i - off] : 0);
        src ^= 1;
        __syncthreads();
    }
    int nodeBase = b << BSHIFT;
    for (int i = t; i < BSIZE; i += 1024) {
        int ex = (i > 0) ? inc[src][i - 1] : 0;
        cur[i] = e0 + ex;
        int node = nodeBase + i;
        if (node < N) {
            offset[node] = e0 + ex;
            dinv[node]   = rsqrtf(1.0f + fsum[i]);
        }
    }
    if (b == 0 && t == 0) offset[N] = E;
    __syncthreads();
    for (int e = e0 + t; e < e1; e += 1024) {
        int2 ed = binned[e];
        unsigned cl = ((unsigned)ed.x) >> 17;
        unsigned row = ((unsigned)ed.x) & 0x1FFFF;
        unsigned hb = (unsigned)__half_as_ushort(__float2half_rn(__int_as_float(ed.y))) & 0x7FFFu;
        int p = atomicAdd(&cur[cl], 1);
        csr[p] = (hb << 17) | row;
    }
}

// ---------------- dense compute (identical to R14) ----------------

__global__ __launch_bounds__(256) void k_gemm_mfma(const float* __restrict__ x,
                                                   const float* __restrict__ W1,
                                                   const float* __restrict__ dinv,
                                                   __half* __restrict__ hs, int n) {
    __shared__ _Float16 xh[64][136];
    __shared__ _Float16 wTh[64][136];
    int t = threadIdx.x;
    int nodeBase = blockIdx.x * 64;

    for (int i = t; i < 2048; i += 256) {
        int r = i >> 5, c4 = i & 31;
        int node = nodeBase + r;
        float4 v = make_float4(0.f, 0.f, 0.f, 0.f);
        if (node < n) v = ((const float4*)x)[node * 32 + c4];
        _Float16* dst = &xh[r][c4 * 4];
        dst[0] = (_Float16)v.x; dst[1] = (_Float16)v.y;
        dst[2] = (_Float16)v.z; dst[3] = (_Float16)v.w;
    }
    for (int i = t; i < 2048; i += 256) {
        int k = i >> 4, c4 = i & 15;
        float4 v = ((const float4*)W1)[k * 16 + c4];
        wTh[c4 * 4 + 0][k] = (_Float16)v.x;
        wTh[c4 * 4 + 1][k] = (_Float16)v.y;
        wTh[c4 * 4 + 2][k] = (_Float16)v.z;
        wTh[c4 * 4 + 3][k] = (_Float16)v.w;
    }
    __syncthreads();

    int w = t >> 6, lane = t & 63;
    int m = lane & 15, quad = lane >> 4;

    f32x4 acc[4] = {{0.f,0.f,0.f,0.f},{0.f,0.f,0.f,0.f},
                    {0.f,0.f,0.f,0.f},{0.f,0.f,0.f,0.f}};
#pragma unroll
    for (int ks = 0; ks < 128; ks += 32) {
        f16x8 a = *(const f16x8*)&xh[w * 16 + m][ks + quad * 8];
#pragma unroll
        for (int ct = 0; ct < 4; ++ct) {
            f16x8 bfr = *(const f16x8*)&wTh[ct * 16 + m][ks + quad * 8];
            acc[ct] = __builtin_amdgcn_mfma_f32_16x16x32_f16(a, bfr, acc[ct], 0, 0, 0);
        }
    }

#pragma unroll
    for (int reg = 0; reg < 4; ++reg) {
        int node = nodeBase + w * 16 + quad * 4 + reg;
        if (node < n) {
            float dv = dinv[node];
#pragma unroll
            for (int ct = 0; ct < 4; ++ct) {
                float v = acc[ct][reg] * dv;
                hs[(size_t)node * 64 + ct * 16 + m] = __float2half_rn(v);
            }
        }
    }
}

// ---------------- agg1 (R16: R14 structure + 32-bit addr + DPP epilogue) ----

__device__ __forceinline__ float dpp_ror8(float x) {
    // row_ror:8 == xor 8 within each 16-lane row
    return __int_as_float(__builtin_amdgcn_update_dpp(
        0, __float_as_int(x), 0x128, 0xF, 0xF, true));
}
template<int CTRL>
__device__ __forceinline__ float dpp_mov(float x) {
    return __int_as_float(__builtin_amdgcn_update_dpp(
        0, __float_as_int(x), CTRL, 0xF, 0xF, true));
}
__device__ __forceinline__ float swz_xor16(float x) {
    // bitmode swizzle: and=0x1F, or=0, xor=0x10 -> lane ^ 16 (within 32-group)
    return __int_as_float(__builtin_amdgcn_ds_swizzle(__float_as_int(x), 0x401F));
}

__global__ __launch_bounds__(256) void k_agg1(const __half* __restrict__ hs,
                                              const int* __restrict__ offset,
                                              const unsigned* __restrict__ csr,
                                              const float* __restrict__ dinv,
                                              const float* __restrict__ b1,
                                              const float* __restrict__ W2,
                                              float* __restrict__ h2s, int n) {
    int wid  = __builtin_amdgcn_readfirstlane(
                   (int)((blockIdx.x * blockDim.x + threadIdx.x) >> 6));
    int lane = threadIdx.x & 63;
    if (wid >= n) return;
    int off0 = __builtin_amdgcn_readfirstlane(offset[wid]);
    int off1 = __builtin_amdgcn_readfirstlane(offset[wid + 1]);
    int g = lane >> 3, s = lane & 7;
    unsigned sbyte = (unsigned)s << 4;          // s * 16 bytes
    const char* hsB = (const char*)hs;

    float acc[8] = {0.f, 0.f, 0.f, 0.f, 0.f, 0.f, 0.f, 0.f};

    {   // self loop (weight 1)
        f16x8 v = *(const f16x8*)(hsB + (((unsigned)wid) << 7) + sbyte);
        if (g == 0) {
#pragma unroll
            for (int k = 0; k < 8; ++k) acc[k] += (float)v[k];
        }
    }

    for (int j = off0; j < off1; j += 32) {
        int   i0 = j + g,      i1 = j + 8 + g,  i2 = j + 16 + g, i3 = j + 24 + g;
        bool  k0 = i0 < off1,  k1 = i1 < off1,  k2 = i2 < off1,  k3 = i3 < off1;
        unsigned eA = csr[k0 ? i0 : off1 - 1];
        unsigned eB = csr[k1 ? i1 : off1 - 1];
        unsigned eC = csr[k2 ? i2 : off1 - 1];
        unsigned eD = csr[k3 ? i3 : off1 - 1];
        f16x8 vA = *(const f16x8*)(hsB + ((eA & 0x1FFFFu) << 7) + sbyte);
        f16x8 vB = *(const f16x8*)(hsB + ((eB & 0x1FFFFu) << 7) + sbyte);
        f16x8 vC = *(const f16x8*)(hsB + ((eC & 0x1FFFFu) << 7) + sbyte);
        f16x8 vD = *(const f16x8*)(hsB + ((eD & 0x1FFFFu) << 7) + sbyte);
        float wA = k0 ? (float)__ushort_as_half((unsigned short)(eA >> 17)) : 0.f;
        float wB = k1 ? (float)__ushort_as_half((unsigned short)(eB >> 17)) : 0.f;
        float wC = k2 ? (float)__ushort_as_half((unsigned short)(eC >> 17)) : 0.f;
        float wD = k3 ? (float)__ushort_as_half((unsigned short)(eD >> 17)) : 0.f;
#pragma unroll
        for (int k = 0; k < 8; ++k) {
            acc[k] += wA * (float)vA[k];
            acc[k] += wB * (float)vB[k];
            acc[k] += wC * (float)vC[k];
            acc[k] += wD * (float)vD[k];
        }
    }

    // reduce over groups (lane bits 3,4,5): DPP ror8 + swizzle xor16 + shfl32
#pragma unroll
    for (int k = 0; k < 8; ++k) {
        float t = acc[k];
        t += dpp_ror8(t);
        t += swz_xor16(t);
        t += __shfl_xor(t, 32);
        acc[k] = t;
    }

    float di = dinv[wid];
    float4 bA = ((const float4*)b1)[s * 2], bB = ((const float4*)b1)[s * 2 + 1];
    float4 wA = ((const float4*)W2)[s * 2], wB = ((const float4*)W2)[s * 2 + 1];
    float p = 0.f;
    p += fmaxf(di * acc[0] + bA.x, 0.f) * wA.x;
    p += fmaxf(di * acc[1] + bA.y, 0.f) * wA.y;
    p += fmaxf(di * acc[2] + bA.z, 0.f) * wA.z;
    p += fmaxf(di * acc[3] + bA.w, 0.f) * wA.w;
    p += fmaxf(di * acc[4] + bB.x, 0.f) * wB.x;
    p += fmaxf(di * acc[5] + bB.y, 0.f) * wB.y;
    p += fmaxf(di * acc[6] + bB.z, 0.f) * wB.z;
    p += fmaxf(di * acc[7] + bB.w, 0.f) * wB.w;
    // reduce over s (lane bits 0,1,2): pure DPP
    p += dpp_mov<0xB1>(p);    // quad_perm [1,0,3,2] == xor 1
    p += dpp_mov<0x4E>(p);    // quad_perm [2,3,0,1] == xor 2
    p += dpp_mov<0x141>(p);   // row_half_mirror == xor 4 after 1,2 reduced
    if (lane == 0) h2s[wid] = di * p;
}

// ---------------- agg2 (identical to R14) ----------------

__global__ __launch_bounds__(256) void k_agg2(const float* __restrict__ h2s,
                                              const int* __restrict__ offset,
                                              const unsigned* __restrict__ csr,
                                              const float* __restrict__ dinv,
                                              const float* __restrict__ b2,
                                              float* __restrict__ out, int n) {
    int wid = __builtin_amdgcn_readfirstlane((int)((blockIdx.x * blockDim.x + threadIdx.x) >> 6));
    int lane = threadIdx.x & 63;
    if (wid >= n) return;
    int off0 = __builtin_amdgcn_readfirstlane(offset[wid]);
    int off1 = __builtin_amdgcn_readfirstlane(offset[wid + 1]);
    float di = dinv[wid];
    float p = 0.f;
    for (int e = off0 + lane; e < off1; e += 64) {
        unsigned ed = csr[e];
        p += (float)__ushort_as_half((unsigned short)(ed >> 17)) * h2s[ed & 0x1FFFF];
    }
#pragma unroll
    for (int s = 32; s > 0; s >>= 1) p += __shfl_xor(p, s);
    if (lane == 0) out[wid] = di * (p + h2s[wid]) + b2[0];
}

extern "C" void kernel_launch(void* const* d_in, const int* in_sizes, int n_in,
                              void* d_out, int out_size, void* d_ws, size_t ws_size,
                              hipStream_t stream) {
    const float* x  = (const float*)d_in[0];
    const int*   ei = (const int*)  d_in[1];
    const float* ea = (const float*)d_in[2];
    const float* W1 = (const float*)d_in[3];
    const float* b1 = (const float*)d_in[4];
    const float* W2 = (const float*)d_in[5];
    const float* b2 = (const float*)d_in[6];
    float* out = (float*)d_out;

    const int N  = in_sizes[0] / 128;   // 100000 (must be <= 131072)
    const int E  = in_sizes[2];         // 3200000
    const int E4 = E / 4;
    const int nbl  = (E4 + 4095) / 4096;        // 16384-edge chunks (196)
    const int nbkt = (N + BSIZE - 1) / BSIZE;   // active buckets (196)

    char* p = (char*)d_ws;
    auto alloc = [&](size_t bytes) -> void* {
        void* r = (void*)p;
        p += (bytes + 255) & ~(size_t)255;
        return r;
    };
    int*       hist   = (int*)      alloc((size_t)nbl * NBUCKET * 4);
    int*       histS  = (int*)      alloc((size_t)NBUCKET * nbl * 4);
    int*       tot    = (int*)      alloc((size_t)NBUCKET * 4);
    int*       base   = (int*)      alloc((size_t)(NBUCKET + 1) * 4);
    int2*      binned = (int2*)     alloc((size_t)E * 8);
    unsigned*  csr    = (unsigned*) alloc((size_t)E * 4);
    int*       offset = (int*)      alloc((size_t)(N + 1) * 4);
    float*     dinv   = (float*)    alloc((size_t)N * 4);
    __half*    hs     = (__half*)   alloc((size_t)N * 64 * 2);
    float*     h2s    = (float*)    alloc((size_t)N * 4);

    const int nb_gemm = (N + 63) / 64;
    const int nb_wave = (N * 64 + 255) / 256;   // one 64-wide wave per node

    k_hist<<<nbl, 1024, 0, stream>>>(ei + E, hist, E4);
    k_scan_bucket<<<NBUCKET, 256, 0, stream>>>(hist, histS, tot, nbl);
    k_scan_tot<<<1, 256, 0, stream>>>(tot, base);
    k_scatter<<<nbl, 1024, 0, stream>>>(ei, ea, histS, base, binned, E, E4, nbl);
    k_finalize<<<nbkt, 1024, 0, stream>>>(binned, base, csr, offset, dinv, N, E);
    k_gemm_mfma<<<nb_gemm, 256, 0, stream>>>(x, W1, dinv, hs, N);
    k_agg1<<<nb_wave, 256, 0, stream>>>(hs, offset, csr, dinv, b1, W2, h2s, N);
    k_agg2<<<nb_wave, 256, 0, stream>>>(h2s, offset, csr, dinv, b2, out, N);
}